// Round 6
// baseline (837.196 us; speedup 1.0000x reference)
//
#include <hip/hip_runtime.h>
#include <math.h>

// TrittentionCube: B=16, S=512, HID=2048, H=4, D=512 (S==D)
// Round 11: proj re-tiled for TLP. Diagnosis: rounds 2/4/5 all pinned at
// ~36% MfmaUtil because 128KB LDS => 1 block/CU, 2 waves/SIMD, barrier-
// locked: nothing fills the read/stage drain. New proj: 128x256 tile,
// 64x64/wave (acc 64 VGPR), BK=32, 3 x 24KB LDS buffers (72KB), counted
// vmcnt(3) depth-2 pipeline, one barrier/K-tile, __launch_bounds__(512,4)
// => 2 blocks/CU, 4 waves/SIMD. Chain (round-10 reg version) unchanged.

typedef _Float16 f16;
typedef f16 f16x8 __attribute__((ext_vector_type(8)));
typedef float f32x4 __attribute__((ext_vector_type(4)));
typedef float f32x16 __attribute__((ext_vector_type(16)));

#define SB_STRIDE 520            // chain S-buffer row stride (halfs)
#define CHAIN_LDS (64 * SB_STRIDE * 2)   // 66,560 B (Sb only)
#define PROJ_LDS  73728          // 3 x 24KB K-tile buffers

static constexpr float SCALE = 0.04419417382415922f;  // 1/sqrt(512)

// async global->LDS, 16B per lane; LDS dest = wave-uniform base + lane*16
__device__ __forceinline__ void gl_lds16(const f16* g, f16* l)
{
    __builtin_amdgcn_global_load_lds(
        (const __attribute__((address_space(1))) void*)g,
        (__attribute__((address_space(3))) void*)l, 16, 0, 0);
}

// ---------------------------------------------------------------- convert
__global__ __launch_bounds__(256) void conv_f32_f16(const float* __restrict__ src,
                                                    f16* __restrict__ dst, int n)
{
    int i = (blockIdx.x * 256 + threadIdx.x) * 8;
    if (i + 8 <= n) {
        float4 a = *(const float4*)(src + i);
        float4 b = *(const float4*)(src + i + 4);
        f16 o[8] = {(f16)a.x, (f16)a.y, (f16)a.z, (f16)a.w,
                    (f16)b.x, (f16)b.y, (f16)b.z, (f16)b.w};
        *(int4*)(dst + i) = *(int4*)o;
    }
}

// ---------------------------------------------------------------- projections
struct ProjPtrs {
    const f16* W[5];
    const float* bias[5];
    f16* dst[5];
};

// C[m,n] = sum_k A[m,k] * W[n,k] + bias[n].  Block 128x256, BK=32,
// 512 threads = 8 waves as 2(M) x 4(N); per-wave output 64x64,
// acc[4][4] of 16x16x32_f16 fragments (64 acc regs).
//
// LDS: 3 buffers x 24KB (A 128x32 = 8KB + B 256x32 = 16KB), fragment-order:
//   A slot s in [0,512): rg=s>>6, kg=(s>>4)&3, r16=s&15; half-off = s*8.
//   B slot s in [0,1024): same with rg=s>>6 in [0,16).
// Staging (3 gl_lds/thread/tile): thread (w,l) writes A slot w*64+l
// (row w*16+(l&15), kg l>>4) and B slots w*64+l, 512+w*64+l (rows
// w*16+(l&15), 128+w*16+(l&15)).  Write half-off == read half-off
// rg*512 + (l>>4)*128 + (l&15)*8: bit-identical fragment convention.
//
// Pipeline (depth 2, 3 buffers, ONE barrier per tile):
//   prologue STAGE(0,t0), STAGE(1,t1)
//   iter kt: vmcnt(3) [tile kt landed; kt+1 in flight] ; barrier
//            [all waves' reads of kt-1 retired] ; STAGE((kt+2)%3 ==
//            (kt-1)%3, kt+2) ; compute tile kt (8 ds_read_b128 + 16 MFMA,
//            compiler-scheduled).
// __launch_bounds__(512,4): <=128 VGPR => 2 blocks/CU, 4 waves/SIMD.
// z==2 (v) and z==4 (cv) stored transposed [bh][d][s] for the chain.
__global__ __launch_bounds__(512, 4) void proj_f16(const f16* __restrict__ A, ProjPtrs P)
{
    extern __shared__ f16 sm[];          // 3 * 12288 halfs = 72 KB
    const int z = blockIdx.z;
    const f16* __restrict__ W = P.W[z];
    const float* __restrict__ bias = P.bias[z];
    f16* __restrict__ dst = P.dst[z];
    const bool tr = (z == 2) || (z == 4);

    const int t    = threadIdx.x;
    const int lane = t & 63;
    const int wave = t >> 6;
    const int wr   = wave >> 2, wc = wave & 3;
    const int bm = blockIdx.y * 128, bn = blockIdx.x * 256;
    const int r16 = lane & 15;
    const int kq  = lane >> 4;           // 0..3

    // per-thread global staging sources (k-offset kq*8 folded in)
    const f16* gA = A + (size_t)(bm + wave * 16 + r16) * 2048 + kq * 8;
    const f16* gB = W + (size_t)(bn + wave * 16 + r16) * 2048 + kq * 8;

// stage K-tile tt into buffer b: A 8KB + B 16KB (3 gl_lds / thread)
#define STAGE(b, tt)                                                \
    {                                                               \
        f16* d_ = sm + (b) * 12288 + wave * 512;                    \
        gl_lds16(gA + (tt) * 32, d_);                               \
        gl_lds16(gB + (tt) * 32, d_ + 4096);                        \
        gl_lds16(gB + (size_t)128 * 2048 + (tt) * 32, d_ + 8192);   \
    }

    f32x4 acc[4][4];
#pragma unroll
    for (int mf = 0; mf < 4; ++mf)
#pragma unroll
        for (int nf = 0; nf < 4; ++nf)
#pragma unroll
            for (int r = 0; r < 4; ++r) acc[mf][nf][r] = 0.f;

    // prologue: tiles 0,1 in flight (6 loads/thread)
    STAGE(0, 0);
    STAGE(1, 1);

    const int lkoff = kq * 128 + r16 * 8;   // frag-read lane offset (halfs)

    int cb = 0;                              // kt % 3
    for (int kt = 0; kt < 64; ++kt) {
        if (kt < 63) asm volatile("s_waitcnt vmcnt(3)" ::: "memory");
        else         asm volatile("s_waitcnt vmcnt(0)" ::: "memory");
        __builtin_amdgcn_s_barrier();
        asm volatile("" ::: "memory");

        if (kt + 2 < 64) {
            int sb = (cb >= 1) ? cb - 1 : 2;   // (kt+2)%3 == (kt-1)%3
            STAGE(sb, kt + 2);
        }

        const f16* bufA = sm + cb * 12288;
        const f16* bufB = bufA + 4096;

        f16x8 af[4], bf[4];
#pragma unroll
        for (int mf = 0; mf < 4; ++mf)
            af[mf] = *(const f16x8*)(bufA + (wr * 4 + mf) * 512 + lkoff);
#pragma unroll
        for (int nf = 0; nf < 4; ++nf)
            bf[nf] = *(const f16x8*)(bufB + (wc * 4 + nf) * 512 + lkoff);

        __builtin_amdgcn_s_setprio(1);
#pragma unroll
        for (int mf = 0; mf < 4; ++mf)
#pragma unroll
            for (int nf = 0; nf < 4; ++nf)
                acc[mf][nf] = __builtin_amdgcn_mfma_f32_16x16x32_f16(
                    af[mf], bf[nf], acc[mf][nf], 0, 0, 0);
        __builtin_amdgcn_s_setprio(0);

        cb = (cb == 2) ? 0 : cb + 1;
    }
#undef STAGE

    // epilogue: C/D mapping col(n)=lane&15, row(m)=(lane>>4)*4+reg
    const int wm = wr * 64, wn = wc * 64;
#pragma unroll
    for (int nf = 0; nf < 4; ++nf) {
        int n = bn + wn + nf * 16 + r16;
        float bb = bias[n];
        int h = n >> 9, d = n & 511;
#pragma unroll
        for (int mf = 0; mf < 4; ++mf) {
            int mbase = bm + wm + mf * 16 + (lane >> 4) * 4;
            int b = mbase >> 9, s0 = mbase & 511;
            if (!tr) {
#pragma unroll
                for (int r = 0; r < 4; ++r)
                    dst[(((size_t)(b * 4 + h)) * 512 + s0 + r) * 512 + d] =
                        (f16)(acc[mf][nf][r] + bb);
            } else {
                f16 pk[4];
#pragma unroll
                for (int r = 0; r < 4; ++r) pk[r] = (f16)(acc[mf][nf][r] + bb);
                *(float2*)(dst + (((size_t)(b * 4 + h)) * 512 + d) * 512 + s0) =
                    *(float2*)pk;
            }
        }
    }
}

// ---------------------------------------------------------------- fused chain
// 512 threads, 8 waves; wave w owns 64-col n-strip, acc[2][2] (64x512 tile).
// acc = Sb(64xK=512) @ Bsrc^T, Bsrc row-major [n][k] (ld=512).
// B fragments load DIRECTLY global->VGPR (each wave's strip is private).
// 2-set pipeline, 16 panels fully unrolled (static set indices).
__device__ __forceinline__ void stage_ntr(const f16* __restrict__ Bsrc,
                                          const f16* __restrict__ Sb,
                                          int t, f32x16 acc[2][2])
{
    const int lane = t & 63;
    const int wave = t >> 6;
    const int l31  = lane & 31;
    const int l5   = (lane >> 5) * 8;

#pragma unroll
    for (int mt = 0; mt < 2; ++mt)
#pragma unroll
        for (int nt = 0; nt < 2; ++nt)
#pragma unroll
            for (int r = 0; r < 16; ++r) acc[mt][nt][r] = 0.f;

    const f16* b0 = Bsrc + (size_t)(wave * 64 + l31) * 512 + l5;
    const f16* b1 = Bsrc + (size_t)(wave * 64 + 32 + l31) * 512 + l5;

    f16x8 bfA[2][2], bfB[2][2];     // [nt][dkh]

#define LDP(S, pp)                                              \
    do {                                                        \
        S[0][0] = *(const f16x8*)(b0 + (pp) * 32);              \
        S[0][1] = *(const f16x8*)(b0 + (pp) * 32 + 16);         \
        S[1][0] = *(const f16x8*)(b1 + (pp) * 32);              \
        S[1][1] = *(const f16x8*)(b1 + (pp) * 32 + 16);         \
    } while (0)

    LDP(bfA, 0);
    LDP(bfB, 1);

#pragma unroll
    for (int p = 0; p < 16; ++p) {
        f16x8 (&S)[2][2] = (p & 1) ? bfB : bfA;   // static under full unroll
#pragma unroll
        for (int dkh = 0; dkh < 2; ++dkh) {
            f16x8 af0 = *(const f16x8*)(Sb + (size_t)l31 * SB_STRIDE + p * 32 + dkh * 16 + l5);
            f16x8 af1 = *(const f16x8*)(Sb + (size_t)(32 + l31) * SB_STRIDE + p * 32 + dkh * 16 + l5);
            acc[0][0] = __builtin_amdgcn_mfma_f32_32x32x16_f16(af0, S[0][dkh], acc[0][0], 0, 0, 0);
            acc[0][1] = __builtin_amdgcn_mfma_f32_32x32x16_f16(af0, S[1][dkh], acc[0][1], 0, 0, 0);
            acc[1][0] = __builtin_amdgcn_mfma_f32_32x32x16_f16(af1, S[0][dkh], acc[1][0], 0, 0, 0);
            acc[1][1] = __builtin_amdgcn_mfma_f32_32x32x16_f16(af1, S[1][dkh], acc[1][1], 0, 0, 0);
        }
        if (p + 2 < 16) LDP(S, p + 2);   // reload just-consumed set for p+2
    }
#undef LDP
}

// C/D mapping 32x32: col=lane&31, row=(reg&3)+8*(reg>>2)+4*(lane>>5)
__device__ __forceinline__ void emit_to_S(f16* __restrict__ Sb, const f32x16 acc[2][2],
                                          int t, float scale)
{
    const int lane = t & 63;
    const int wn = (t >> 6) * 64;
#pragma unroll
    for (int mt = 0; mt < 2; ++mt)
#pragma unroll
        for (int nt = 0; nt < 2; ++nt) {
            int col = wn + nt * 32 + (lane & 31);
#pragma unroll
            for (int r = 0; r < 16; ++r) {
                int row = mt * 32 + (r & 3) + 8 * (r >> 2) + 4 * (lane >> 5);
                Sb[(size_t)row * SB_STRIDE + col] = (f16)(acc[mt][nt][r] * scale);
            }
        }
}

__global__ __launch_bounds__(512, 4) void chain_f16(
    const f16* __restrict__ q16, const f16* __restrict__ k16,
    const f16* __restrict__ ck16, const f16* __restrict__ vt16,
    const f16* __restrict__ cvt16, float* __restrict__ out)
{
    extern __shared__ f16 smem[];
    f16* Sb = smem;                       // [64][SB_STRIDE] = 66,560 B
    const int t = threadIdx.x;
    const int bh = blockIdx.x >> 3;
    const int q0 = (blockIdx.x & 7) * 64;
    const size_t SB = 512 * 512;

    // stage Q[q0..q0+64) into Sbuf
    const f16* Q = q16 + bh * SB;
    for (int i = t; i < 4096; i += 512) {
        int row = i >> 6, c = (i & 63) * 8;
        *(int4*)(Sb + (size_t)row * SB_STRIDE + c) =
            *(const int4*)(Q + (size_t)(q0 + row) * 512 + c);
    }
    __syncthreads();

    f32x16 acc[2][2];

    // S1 = Q @ K^T
    stage_ntr(k16 + bh * SB, Sb, t, acc);
    __syncthreads();                 // all Sb reads done before overwrite
    emit_to_S(Sb, acc, t, 1.0f);
    __syncthreads();

    // S2 = S1 @ CK^T * SCALE
    stage_ntr(ck16 + bh * SB, Sb, t, acc);
    __syncthreads();
    emit_to_S(Sb, acc, t, SCALE);
    __syncthreads();

    // softmax rows (wave w -> rows 8w..8w+8)
    {
        const int lane = t & 63;
        const int wave = t >> 6;
        for (int rr = 0; rr < 8; ++rr) {
            int r = wave * 8 + rr;
            f16x8 xv = *(const f16x8*)(Sb + (size_t)r * SB_STRIDE + lane * 8);
            float x[8];
            float mx = -1e30f;
#pragma unroll
            for (int j = 0; j < 8; ++j) { x[j] = (float)xv[j]; mx = fmaxf(mx, x[j]); }
#pragma unroll
            for (int o = 32; o > 0; o >>= 1) mx = fmaxf(mx, __shfl_xor(mx, o));
            float s = 0.f;
#pragma unroll
            for (int j = 0; j < 8; ++j) { x[j] = __expf(x[j] - mx); s += x[j]; }
#pragma unroll
            for (int o = 32; o > 0; o >>= 1) s += __shfl_xor(s, o);
            float inv = 1.0f / s;
            f16x8 ov;
#pragma unroll
            for (int j = 0; j < 8; ++j) ov[j] = (f16)(x[j] * inv);
            *(f16x8*)(Sb + (size_t)r * SB_STRIDE + lane * 8) = ov;
        }
    }
    __syncthreads();

    // C1 = P @ V   (Vt is [bh][d][s]: NT-ready)
    stage_ntr(vt16 + bh * SB, Sb, t, acc);
    __syncthreads();
    emit_to_S(Sb, acc, t, 1.0f);
    __syncthreads();

    // OUT = C1 @ CV (CVt NT-ready), merge-heads store f32
    stage_ntr(cvt16 + bh * SB, Sb, t, acc);
    {
        const int lane = t & 63;
        const int wn = (t >> 6) * 64;
        int b = bh >> 2, h = bh & 3;
#pragma unroll
        for (int mt = 0; mt < 2; ++mt)
#pragma unroll
            for (int nt = 0; nt < 2; ++nt) {
                int col = h * 512 + wn + nt * 32 + (lane & 31);
#pragma unroll
                for (int r = 0; r < 16; ++r) {
                    int row = q0 + mt * 32 + (r & 3) + 8 * (r >> 2) + 4 * (lane >> 5);
                    out[((size_t)b * 512 + row) * 2048 + col] = acc[mt][nt][r];
                }
            }
    }
}

// ---------------------------------------------------------------- host
extern "C" void kernel_launch(void* const* d_in, const int* in_sizes, int n_in,
                              void* d_out, int out_size, void* d_ws, size_t ws_size,
                              hipStream_t stream)
{
    const float* hs = (const float*)d_in[0];
    const float* Wf[5] = {(const float*)d_in[1], (const float*)d_in[3],
                          (const float*)d_in[5], (const float*)d_in[7],
                          (const float*)d_in[9]};
    const float* bf[5] = {(const float*)d_in[2], (const float*)d_in[4],
                          (const float*)d_in[6], (const float*)d_in[8],
                          (const float*)d_in[10]};
    float* out = (float*)d_out;

    hipFuncSetAttribute((const void*)chain_f16,
                        hipFuncAttributeMaxDynamicSharedMemorySize, CHAIN_LDS);
    hipFuncSetAttribute((const void*)proj_f16,
                        hipFuncAttributeMaxDynamicSharedMemorySize, PROJ_LDS);

    f16* ws = (f16*)d_ws;
    const size_t WELEM = 2048ULL * 2048;      // 4,194,304
    const size_t FULLACT = 64ULL * 512 * 512; // 16,777,216

    f16* W16[5];
    for (int i = 0; i < 5; ++i) W16[i] = ws + i * WELEM;
    f16* after_w = ws + 5 * WELEM;

    for (int i = 0; i < 5; ++i)
        conv_f32_f16<<<dim3(WELEM / 2048), 256, 0, stream>>>(Wf[i], W16[i], (int)WELEM);

    size_t full_need = (5 * WELEM + FULLACT + 5 * FULLACT) * sizeof(f16);  // 243,269,632
    if (ws_size >= full_need) {
        // ---------------- full path ----------------
        f16* hs16 = after_w;
        f16* act[5];
        for (int i = 0; i < 5; ++i) act[i] = after_w + FULLACT + i * FULLACT;

        conv_f32_f16<<<dim3(FULLACT / 2048), 256, 0, stream>>>(hs, hs16, (int)FULLACT);

        ProjPtrs P;
        for (int i = 0; i < 5; ++i) { P.W[i] = W16[i]; P.bias[i] = bf[i]; P.dst[i] = act[i]; }
        proj_f16<<<dim3(8, 64, 5), 512, PROJ_LDS, stream>>>(hs16, P);

        // act order: q,k,v^T,ck,cv^T -> chain(q,k,ck,vt,cvt)
        chain_f16<<<dim3(512), 512, CHAIN_LDS, stream>>>(
            act[0], act[1], act[3], act[2], act[4], out);
    } else {
        // ---------------- chunked path (54.5 MB ws) ----------------
        const size_t CHROW = 1048576ULL;      // 512*2048 elems per batch
        const size_t CHACT = 4ULL * 512 * 512;
        f16* hs16c = after_w;
        f16* act[5];
        for (int i = 0; i < 5; ++i) act[i] = after_w + CHROW + i * CHACT;

        ProjPtrs P;
        for (int i = 0; i < 5; ++i) { P.W[i] = W16[i]; P.bias[i] = bf[i]; P.dst[i] = act[i]; }

        for (int c = 0; c < 16; ++c) {
            conv_f32_f16<<<dim3(CHROW / 2048), 256, 0, stream>>>(
                hs + c * CHROW, hs16c, (int)CHROW);
            proj_f16<<<dim3(8, 16, 5), 512, PROJ_LDS, stream>>>(hs16c, P);
            chain_f16<<<dim3(32), 512, CHAIN_LDS, stream>>>(
                act[0], act[1], act[3], act[2], act[4], out + c * CHROW);
        }
    }

    (void)in_sizes; (void)n_in; (void)out_size;
}

// Round 7
// 728.977 us; speedup vs baseline: 1.1485x; 1.1485x over previous
//
#include <hip/hip_runtime.h>
#include <math.h>

// TrittentionCube: B=16, S=512, HID=2048, H=4, D=512 (S==D)
// Round 12: proj reverted to the round-5 verified 8-phase version (421 us;
// round-11's smaller-tile TLP experiment regressed to 534 and is dropped).
// Chain gets an XCD-aware work remap: bh = bx % 64 puts all 8 q0-blocks of
// a bh on the SAME XCD (bx = bh mod 8), so the 2MB K/CK/V/CV panel set is
// fetched into one L2 once instead of 8 XCDs x 8 re-fetches. Chain was
// ~300us for 68.7 GFLOP = fetch-bound by this amplification.

typedef _Float16 f16;
typedef f16 f16x8 __attribute__((ext_vector_type(8)));
typedef float f32x4 __attribute__((ext_vector_type(4)));
typedef float f32x16 __attribute__((ext_vector_type(16)));

#define SB_STRIDE 520            // chain S-buffer row stride (halfs)
#define CHAIN_LDS (64 * SB_STRIDE * 2)   // 66,560 B (Sb only)
#define PROJ_LDS  131072         // 2 x 64KB K-tile buffers

static constexpr float SCALE = 0.04419417382415922f;  // 1/sqrt(512)

// async global->LDS, 16B per lane; LDS dest = wave-uniform base + lane*16
__device__ __forceinline__ void gl_lds16(const f16* g, f16* l)
{
    __builtin_amdgcn_global_load_lds(
        (const __attribute__((address_space(1))) void*)g,
        (__attribute__((address_space(3))) void*)l, 16, 0, 0);
}

// ---------------------------------------------------------------- convert
__global__ __launch_bounds__(256) void conv_f32_f16(const float* __restrict__ src,
                                                    f16* __restrict__ dst, int n)
{
    int i = (blockIdx.x * 256 + threadIdx.x) * 8;
    if (i + 8 <= n) {
        float4 a = *(const float4*)(src + i);
        float4 b = *(const float4*)(src + i + 4);
        f16 o[8] = {(f16)a.x, (f16)a.y, (f16)a.z, (f16)a.w,
                    (f16)b.x, (f16)b.y, (f16)b.z, (f16)b.w};
        *(int4*)(dst + i) = *(int4*)o;
    }
}

// ---------------------------------------------------------------- projections
struct ProjPtrs {
    const f16* W[5];
    const float* bias[5];
    f16* dst[5];
};

// (verified round-5 version: 256x256, BK=64, 8-phase, 421 us, MfmaUtil 36%)
__global__ __launch_bounds__(512, 2) void proj_f16(const f16* __restrict__ A, ProjPtrs P)
{
    extern __shared__ f16 sm[];          // 2 * 32768 halfs = 128 KB
    const int z = blockIdx.z;
    const f16* __restrict__ W = P.W[z];
    const float* __restrict__ bias = P.bias[z];
    f16* __restrict__ dst = P.dst[z];
    const bool tr = (z == 2) || (z == 4);

    const int t    = threadIdx.x;
    const int lane = t & 63;
    const int wave = t >> 6;
    const int wr   = wave >> 2, wc = wave & 3;
    const int bm = blockIdx.y * 256, bn = blockIdx.x * 256;
    const int r16 = lane & 15;
    const int kq  = lane >> 4;           // 0..3

    const f16* gA = A + (size_t)(bm + (wave >> 1) * 16 + r16) * 2048 + ((wave & 1) * 4 + kq) * 8;
    const f16* gB = W + (size_t)(bn + (wave >> 1) * 16 + r16) * 2048 + ((wave & 1) * 4 + kq) * 8;
    const int stoff = wave * 512;        // wave-uniform LDS stage offset (halfs)

#define STG_A(c, h, tt)                                                     \
    {                                                                       \
        f16* d_ = sm + (c) * 32768 + (h) * 8192 + stoff;                    \
        gl_lds16(gA + (size_t)((h) * 128) * 2048 + (tt) * 64, d_);          \
        gl_lds16(gA + (size_t)((h) * 128 + 64) * 2048 + (tt) * 64, d_ + 4096); \
    }
#define STG_B(c, h, tt)                                                     \
    {                                                                       \
        f16* d_ = sm + (c) * 32768 + 16384 + (h) * 8192 + stoff;            \
        gl_lds16(gB + (size_t)((h) * 128) * 2048 + (tt) * 64, d_);          \
        gl_lds16(gB + (size_t)((h) * 128 + 64) * 2048 + (tt) * 64, d_ + 4096); \
    }

    f32x4 acc[8][4];
#pragma unroll
    for (int mf = 0; mf < 8; ++mf)
#pragma unroll
        for (int nf = 0; nf < 4; ++nf)
#pragma unroll
            for (int r = 0; r < 4; ++r) acc[mf][nf][r] = 0.f;

    STG_A(0, 0, 0); STG_A(0, 1, 0); STG_B(0, 0, 0); STG_B(0, 1, 0);
    STG_A(1, 0, 1); STG_A(1, 1, 1);
    asm volatile("s_waitcnt vmcnt(4)" ::: "memory");   // tile 0 landed
    __builtin_amdgcn_s_barrier();
    asm volatile("" ::: "memory");

    const int aoff = kq * 128 + r16 * 8;   // frag-read lane offset (halfs)

    f16x8 af[8][2], bf[4][2];

    for (int kt = 0; kt < 32; ++kt) {
        const int cur = kt & 1, nxt = cur ^ 1;
        const f16* pa = sm + cur * 32768 + wr * 8192 + aoff;
        const f16* pb = sm + cur * 32768 + 16384 + (wc >> 1) * 8192 + (wc & 1) * 4096 + aoff;

        // ---------------- P1: af[0-3], bf[0-1]; stage B0(kt+1); MFMA m0n0
#pragma unroll
        for (int mf = 0; mf < 4; ++mf)
#pragma unroll
            for (int dk = 0; dk < 2; ++dk)
                af[mf][dk] = *(const f16x8*)(pa + mf * 1024 + dk * 512);
#pragma unroll
        for (int nf = 0; nf < 2; ++nf)
#pragma unroll
            for (int dk = 0; dk < 2; ++dk)
                bf[nf][dk] = *(const f16x8*)(pb + nf * 1024 + dk * 512);
        if (kt + 1 < 32) STG_B(nxt, 0, kt + 1);
        asm volatile("" ::: "memory");
        __builtin_amdgcn_s_barrier();
        asm volatile("s_waitcnt lgkmcnt(0)" ::: "memory");
        __builtin_amdgcn_sched_barrier(0);
        __builtin_amdgcn_s_setprio(1);
#pragma unroll
        for (int mf = 0; mf < 4; ++mf)
#pragma unroll
            for (int nf = 0; nf < 2; ++nf)
#pragma unroll
                for (int dk = 0; dk < 2; ++dk)
                    acc[mf][nf] = __builtin_amdgcn_mfma_f32_16x16x32_f16(
                        af[mf][dk], bf[nf][dk], acc[mf][nf], 0, 0, 0);
        __builtin_amdgcn_s_setprio(0);
        asm volatile("" ::: "memory");
        __builtin_amdgcn_s_barrier();
        asm volatile("" ::: "memory");

        // ---------------- P2: af[4-7]; stage B1(kt+1); MFMA m1n0
#pragma unroll
        for (int mf = 4; mf < 8; ++mf)
#pragma unroll
            for (int dk = 0; dk < 2; ++dk)
                af[mf][dk] = *(const f16x8*)(pa + mf * 1024 + dk * 512);
        if (kt + 1 < 32) STG_B(nxt, 1, kt + 1);
        asm volatile("" ::: "memory");
        __builtin_amdgcn_s_barrier();
        asm volatile("s_waitcnt lgkmcnt(0)" ::: "memory");
        __builtin_amdgcn_sched_barrier(0);
        __builtin_amdgcn_s_setprio(1);
#pragma unroll
        for (int mf = 4; mf < 8; ++mf)
#pragma unroll
            for (int nf = 0; nf < 2; ++nf)
#pragma unroll
                for (int dk = 0; dk < 2; ++dk)
                    acc[mf][nf] = __builtin_amdgcn_mfma_f32_16x16x32_f16(
                        af[mf][dk], bf[nf][dk], acc[mf][nf], 0, 0, 0);
        __builtin_amdgcn_s_setprio(0);
        asm volatile("" ::: "memory");
        __builtin_amdgcn_s_barrier();
        asm volatile("" ::: "memory");

        // ---------------- P3: bf[2-3]; stage A0(kt+2); MFMA m0n1
#pragma unroll
        for (int nf = 2; nf < 4; ++nf)
#pragma unroll
            for (int dk = 0; dk < 2; ++dk)
                bf[nf][dk] = *(const f16x8*)(pb + nf * 1024 + dk * 512);
        if (kt + 2 < 32) STG_A(cur, 0, kt + 2);
        asm volatile("" ::: "memory");
        __builtin_amdgcn_s_barrier();
        asm volatile("s_waitcnt lgkmcnt(0)" ::: "memory");
        __builtin_amdgcn_sched_barrier(0);
        __builtin_amdgcn_s_setprio(1);
#pragma unroll
        for (int mf = 0; mf < 4; ++mf)
#pragma unroll
            for (int nf = 2; nf < 4; ++nf)
#pragma unroll
                for (int dk = 0; dk < 2; ++dk)
                    acc[mf][nf] = __builtin_amdgcn_mfma_f32_16x16x32_f16(
                        af[mf][dk], bf[nf][dk], acc[mf][nf], 0, 0, 0);
        __builtin_amdgcn_s_setprio(0);
        asm volatile("" ::: "memory");
        __builtin_amdgcn_s_barrier();
        asm volatile("" ::: "memory");

        // ---------------- P4: stage A1(kt+2); vmcnt; MFMA m1n1
        if (kt + 2 < 32) STG_A(cur, 1, kt + 2);
        if (kt < 30) asm volatile("s_waitcnt vmcnt(4)" ::: "memory");
        else         asm volatile("s_waitcnt vmcnt(0)" ::: "memory");
        __builtin_amdgcn_s_barrier();
        asm volatile("" ::: "memory");
        __builtin_amdgcn_s_setprio(1);
#pragma unroll
        for (int mf = 4; mf < 8; ++mf)
#pragma unroll
            for (int nf = 2; nf < 4; ++nf)
#pragma unroll
                for (int dk = 0; dk < 2; ++dk)
                    acc[mf][nf] = __builtin_amdgcn_mfma_f32_16x16x32_f16(
                        af[mf][dk], bf[nf][dk], acc[mf][nf], 0, 0, 0);
        __builtin_amdgcn_s_setprio(0);
        asm volatile("" ::: "memory");
        __builtin_amdgcn_s_barrier();
        asm volatile("" ::: "memory");
    }
#undef STG_A
#undef STG_B

    // epilogue: C/D mapping col(n)=lane&15, row(m)=(lane>>4)*4+reg
    const int wm = wr * 128, wn = wc * 64;
#pragma unroll
    for (int nf = 0; nf < 4; ++nf) {
        int n = bn + wn + nf * 16 + r16;
        float bb = bias[n];
        int h = n >> 9, d = n & 511;
#pragma unroll
        for (int mf = 0; mf < 8; ++mf) {
            int mbase = bm + wm + mf * 16 + (lane >> 4) * 4;
            int b = mbase >> 9, s0 = mbase & 511;
            if (!tr) {
#pragma unroll
                for (int r = 0; r < 4; ++r)
                    dst[(((size_t)(b * 4 + h)) * 512 + s0 + r) * 512 + d] =
                        (f16)(acc[mf][nf][r] + bb);
            } else {
                f16 pk[4];
#pragma unroll
                for (int r = 0; r < 4; ++r) pk[r] = (f16)(acc[mf][nf][r] + bb);
                *(float2*)(dst + (((size_t)(b * 4 + h)) * 512 + d) * 512 + s0) =
                    *(float2*)pk;
            }
        }
    }
}

// ---------------------------------------------------------------- fused chain
// 512 threads, 8 waves; wave w owns 64-col n-strip, acc[2][2] (64x512 tile).
// acc = Sb(64xK=512) @ Bsrc^T, Bsrc row-major [n][k] (ld=512).
// B fragments load DIRECTLY global->VGPR (each wave's strip is private).
// 2-set pipeline, 16 panels fully unrolled (static set indices).
__device__ __forceinline__ void stage_ntr(const f16* __restrict__ Bsrc,
                                          const f16* __restrict__ Sb,
                                          int t, f32x16 acc[2][2])
{
    const int lane = t & 63;
    const int wave = t >> 6;
    const int l31  = lane & 31;
    const int l5   = (lane >> 5) * 8;

#pragma unroll
    for (int mt = 0; mt < 2; ++mt)
#pragma unroll
        for (int nt = 0; nt < 2; ++nt)
#pragma unroll
            for (int r = 0; r < 16; ++r) acc[mt][nt][r] = 0.f;

    const f16* b0 = Bsrc + (size_t)(wave * 64 + l31) * 512 + l5;
    const f16* b1 = Bsrc + (size_t)(wave * 64 + 32 + l31) * 512 + l5;

    f16x8 bfA[2][2], bfB[2][2];     // [nt][dkh]

#define LDP(S, pp)                                              \
    do {                                                        \
        S[0][0] = *(const f16x8*)(b0 + (pp) * 32);              \
        S[0][1] = *(const f16x8*)(b0 + (pp) * 32 + 16);         \
        S[1][0] = *(const f16x8*)(b1 + (pp) * 32);              \
        S[1][1] = *(const f16x8*)(b1 + (pp) * 32 + 16);         \
    } while (0)

    LDP(bfA, 0);
    LDP(bfB, 1);

#pragma unroll
    for (int p = 0; p < 16; ++p) {
        f16x8 (&S)[2][2] = (p & 1) ? bfB : bfA;   // static under full unroll
#pragma unroll
        for (int dkh = 0; dkh < 2; ++dkh) {
            f16x8 af0 = *(const f16x8*)(Sb + (size_t)l31 * SB_STRIDE + p * 32 + dkh * 16 + l5);
            f16x8 af1 = *(const f16x8*)(Sb + (size_t)(32 + l31) * SB_STRIDE + p * 32 + dkh * 16 + l5);
            acc[0][0] = __builtin_amdgcn_mfma_f32_32x32x16_f16(af0, S[0][dkh], acc[0][0], 0, 0, 0);
            acc[0][1] = __builtin_amdgcn_mfma_f32_32x32x16_f16(af0, S[1][dkh], acc[0][1], 0, 0, 0);
            acc[1][0] = __builtin_amdgcn_mfma_f32_32x32x16_f16(af1, S[0][dkh], acc[1][0], 0, 0, 0);
            acc[1][1] = __builtin_amdgcn_mfma_f32_32x32x16_f16(af1, S[1][dkh], acc[1][1], 0, 0, 0);
        }
        if (p + 2 < 16) LDP(S, p + 2);   // reload just-consumed set for p+2
    }
#undef LDP
}

// C/D mapping 32x32: col=lane&31, row=(reg&3)+8*(reg>>2)+4*(lane>>5)
__device__ __forceinline__ void emit_to_S(f16* __restrict__ Sb, const f32x16 acc[2][2],
                                          int t, float scale)
{
    const int lane = t & 63;
    const int wn = (t >> 6) * 64;
#pragma unroll
    for (int mt = 0; mt < 2; ++mt)
#pragma unroll
        for (int nt = 0; nt < 2; ++nt) {
            int col = wn + nt * 32 + (lane & 31);
#pragma unroll
            for (int r = 0; r < 16; ++r) {
                int row = mt * 32 + (r & 3) + 8 * (r >> 2) + 4 * (lane >> 5);
                Sb[(size_t)row * SB_STRIDE + col] = (f16)(acc[mt][nt][r] * scale);
            }
        }
}

// bhmask/q0shift: XCD-aware remap. bh = bx & bhmask => all q0-blocks of a
// bh satisfy bx === bh (mod 8) -> same XCD -> its 4 x 512KB panels are
// fetched into ONE L2 and shared by the 8 co-resident q0-blocks.
__global__ __launch_bounds__(512, 4) void chain_f16(
    const f16* __restrict__ q16, const f16* __restrict__ k16,
    const f16* __restrict__ ck16, const f16* __restrict__ vt16,
    const f16* __restrict__ cvt16, float* __restrict__ out,
    int bhmask, int q0shift)
{
    extern __shared__ f16 smem[];
    f16* Sb = smem;                       // [64][SB_STRIDE] = 66,560 B
    const int t = threadIdx.x;
    const int bh = blockIdx.x & bhmask;
    const int q0 = (blockIdx.x >> q0shift) * 64;
    const size_t SB = 512 * 512;

    // stage Q[q0..q0+64) into Sbuf
    const f16* Q = q16 + bh * SB;
    for (int i = t; i < 4096; i += 512) {
        int row = i >> 6, c = (i & 63) * 8;
        *(int4*)(Sb + (size_t)row * SB_STRIDE + c) =
            *(const int4*)(Q + (size_t)(q0 + row) * 512 + c);
    }
    __syncthreads();

    f32x16 acc[2][2];

    // S1 = Q @ K^T
    stage_ntr(k16 + bh * SB, Sb, t, acc);
    __syncthreads();                 // all Sb reads done before overwrite
    emit_to_S(Sb, acc, t, 1.0f);
    __syncthreads();

    // S2 = S1 @ CK^T * SCALE
    stage_ntr(ck16 + bh * SB, Sb, t, acc);
    __syncthreads();
    emit_to_S(Sb, acc, t, SCALE);
    __syncthreads();

    // softmax rows (wave w -> rows 8w..8w+8)
    {
        const int lane = t & 63;
        const int wave = t >> 6;
        for (int rr = 0; rr < 8; ++rr) {
            int r = wave * 8 + rr;
            f16x8 xv = *(const f16x8*)(Sb + (size_t)r * SB_STRIDE + lane * 8);
            float x[8];
            float mx = -1e30f;
#pragma unroll
            for (int j = 0; j < 8; ++j) { x[j] = (float)xv[j]; mx = fmaxf(mx, x[j]); }
#pragma unroll
            for (int o = 32; o > 0; o >>= 1) mx = fmaxf(mx, __shfl_xor(mx, o));
            float s = 0.f;
#pragma unroll
            for (int j = 0; j < 8; ++j) { x[j] = __expf(x[j] - mx); s += x[j]; }
#pragma unroll
            for (int o = 32; o > 0; o >>= 1) s += __shfl_xor(s, o);
            float inv = 1.0f / s;
            f16x8 ov;
#pragma unroll
            for (int j = 0; j < 8; ++j) ov[j] = (f16)(x[j] * inv);
            *(f16x8*)(Sb + (size_t)r * SB_STRIDE + lane * 8) = ov;
        }
    }
    __syncthreads();

    // C1 = P @ V   (Vt is [bh][d][s]: NT-ready)
    stage_ntr(vt16 + bh * SB, Sb, t, acc);
    __syncthreads();
    emit_to_S(Sb, acc, t, 1.0f);
    __syncthreads();

    // OUT = C1 @ CV (CVt NT-ready), merge-heads store f32
    stage_ntr(cvt16 + bh * SB, Sb, t, acc);
    {
        const int lane = t & 63;
        const int wn = (t >> 6) * 64;
        int b = bh >> 2, h = bh & 3;
#pragma unroll
        for (int mt = 0; mt < 2; ++mt)
#pragma unroll
            for (int nt = 0; nt < 2; ++nt) {
                int col = h * 512 + wn + nt * 32 + (lane & 31);
#pragma unroll
                for (int r = 0; r < 16; ++r) {
                    int row = q0 + mt * 32 + (r & 3) + 8 * (r >> 2) + 4 * (lane >> 5);
                    out[((size_t)b * 512 + row) * 2048 + col] = acc[mt][nt][r];
                }
            }
    }
}

// ---------------------------------------------------------------- host
extern "C" void kernel_launch(void* const* d_in, const int* in_sizes, int n_in,
                              void* d_out, int out_size, void* d_ws, size_t ws_size,
                              hipStream_t stream)
{
    const float* hs = (const float*)d_in[0];
    const float* Wf[5] = {(const float*)d_in[1], (const float*)d_in[3],
                          (const float*)d_in[5], (const float*)d_in[7],
                          (const float*)d_in[9]};
    const float* bf[5] = {(const float*)d_in[2], (const float*)d_in[4],
                          (const float*)d_in[6], (const float*)d_in[8],
                          (const float*)d_in[10]};
    float* out = (float*)d_out;

    hipFuncSetAttribute((const void*)chain_f16,
                        hipFuncAttributeMaxDynamicSharedMemorySize, CHAIN_LDS);
    hipFuncSetAttribute((const void*)proj_f16,
                        hipFuncAttributeMaxDynamicSharedMemorySize, PROJ_LDS);

    f16* ws = (f16*)d_ws;
    const size_t WELEM = 2048ULL * 2048;      // 4,194,304
    const size_t FULLACT = 64ULL * 512 * 512; // 16,777,216

    f16* W16[5];
    for (int i = 0; i < 5; ++i) W16[i] = ws + i * WELEM;
    f16* after_w = ws + 5 * WELEM;

    for (int i = 0; i < 5; ++i)
        conv_f32_f16<<<dim3(WELEM / 2048), 256, 0, stream>>>(Wf[i], W16[i], (int)WELEM);

    size_t full_need = (5 * WELEM + FULLACT + 5 * FULLACT) * sizeof(f16);  // 243,269,632
    if (ws_size >= full_need) {
        // ---------------- full path ----------------
        f16* hs16 = after_w;
        f16* act[5];
        for (int i = 0; i < 5; ++i) act[i] = after_w + FULLACT + i * FULLACT;

        conv_f32_f16<<<dim3(FULLACT / 2048), 256, 0, stream>>>(hs, hs16, (int)FULLACT);

        ProjPtrs P;
        for (int i = 0; i < 5; ++i) { P.W[i] = W16[i]; P.bias[i] = bf[i]; P.dst[i] = act[i]; }
        proj_f16<<<dim3(8, 32, 5), 512, PROJ_LDS, stream>>>(hs16, P);

        // act order: q,k,v^T,ck,cv^T -> chain(q,k,ck,vt,cvt)
        chain_f16<<<dim3(512), 512, CHAIN_LDS, stream>>>(
            act[0], act[1], act[3], act[2], act[4], out, 63, 6);
    } else {
        // ---------------- chunked path (54.5 MB ws) ----------------
        const size_t CHROW = 1048576ULL;      // 512*2048 elems per batch
        const size_t CHACT = 4ULL * 512 * 512;
        f16* hs16c = after_w;
        f16* act[5];
        for (int i = 0; i < 5; ++i) act[i] = after_w + CHROW + i * CHACT;

        ProjPtrs P;
        for (int i = 0; i < 5; ++i) { P.W[i] = W16[i]; P.bias[i] = bf[i]; P.dst[i] = act[i]; }

        for (int c = 0; c < 16; ++c) {
            conv_f32_f16<<<dim3(CHROW / 2048), 256, 0, stream>>>(
                hs + c * CHROW, hs16c, (int)CHROW);
            proj_f16<<<dim3(8, 2, 5), 512, PROJ_LDS, stream>>>(hs16c, P);
            chain_f16<<<dim3(32), 512, CHAIN_LDS, stream>>>(
                act[0], act[1], act[3], act[2], act[4], out + c * CHROW, 3, 2);
        }
    }

    (void)in_sizes; (void)n_in; (void)out_size;
}

// Round 8
// 663.601 us; speedup vs baseline: 1.2616x; 1.0985x over previous
//
#include <hip/hip_runtime.h>
#include <math.h>

// TrittentionCube: B=16, S=512, HID=2048, H=4, D=512 (S==D)
// Round 13: chain QBLK 64 -> 128. Chain is fetch-volume-bound (~1.1GB =
// 8 q0-blocks x 4x512KB panels per bh; 16MB/XCD working set defeats L2
// reuse). Doubling rows per block halves the redundant panel fetch
// (256 blocks x ~2.2MB = 0.56GB). Sb = 128x520 halfs = 133KB LDS,
// 8 waves each own a 64-col strip over all 128 rows (acc[4][2]).
// Proj (round-5 verified, 423us) and conv byte-identical.

typedef _Float16 f16;
typedef f16 f16x8 __attribute__((ext_vector_type(8)));
typedef float f32x4 __attribute__((ext_vector_type(4)));
typedef float f32x16 __attribute__((ext_vector_type(16)));

#define SB_STRIDE 520            // chain S-buffer row stride (halfs)
#define QBLK 128
#define CHAIN_LDS (QBLK * SB_STRIDE * 2)   // 133,120 B (Sb only)
#define PROJ_LDS  131072         // 2 x 64KB K-tile buffers

static constexpr float SCALE = 0.04419417382415922f;  // 1/sqrt(512)

// async global->LDS, 16B per lane; LDS dest = wave-uniform base + lane*16
__device__ __forceinline__ void gl_lds16(const f16* g, f16* l)
{
    __builtin_amdgcn_global_load_lds(
        (const __attribute__((address_space(1))) void*)g,
        (__attribute__((address_space(3))) void*)l, 16, 0, 0);
}

// ---------------------------------------------------------------- convert
__global__ __launch_bounds__(256) void conv_f32_f16(const float* __restrict__ src,
                                                    f16* __restrict__ dst, int n)
{
    int i = (blockIdx.x * 256 + threadIdx.x) * 8;
    if (i + 8 <= n) {
        float4 a = *(const float4*)(src + i);
        float4 b = *(const float4*)(src + i + 4);
        f16 o[8] = {(f16)a.x, (f16)a.y, (f16)a.z, (f16)a.w,
                    (f16)b.x, (f16)b.y, (f16)b.z, (f16)b.w};
        *(int4*)(dst + i) = *(int4*)o;
    }
}

// ---------------------------------------------------------------- projections
struct ProjPtrs {
    const f16* W[5];
    const float* bias[5];
    f16* dst[5];
};

// (verified round-5 version: 256x256, BK=64, 8-phase, 421 us, MfmaUtil 36%)
__global__ __launch_bounds__(512, 2) void proj_f16(const f16* __restrict__ A, ProjPtrs P)
{
    extern __shared__ f16 sm[];          // 2 * 32768 halfs = 128 KB
    const int z = blockIdx.z;
    const f16* __restrict__ W = P.W[z];
    const float* __restrict__ bias = P.bias[z];
    f16* __restrict__ dst = P.dst[z];
    const bool tr = (z == 2) || (z == 4);

    const int t    = threadIdx.x;
    const int lane = t & 63;
    const int wave = t >> 6;
    const int wr   = wave >> 2, wc = wave & 3;
    const int bm = blockIdx.y * 256, bn = blockIdx.x * 256;
    const int r16 = lane & 15;
    const int kq  = lane >> 4;           // 0..3

    const f16* gA = A + (size_t)(bm + (wave >> 1) * 16 + r16) * 2048 + ((wave & 1) * 4 + kq) * 8;
    const f16* gB = W + (size_t)(bn + (wave >> 1) * 16 + r16) * 2048 + ((wave & 1) * 4 + kq) * 8;
    const int stoff = wave * 512;        // wave-uniform LDS stage offset (halfs)

#define STG_A(c, h, tt)                                                     \
    {                                                                       \
        f16* d_ = sm + (c) * 32768 + (h) * 8192 + stoff;                    \
        gl_lds16(gA + (size_t)((h) * 128) * 2048 + (tt) * 64, d_);          \
        gl_lds16(gA + (size_t)((h) * 128 + 64) * 2048 + (tt) * 64, d_ + 4096); \
    }
#define STG_B(c, h, tt)                                                     \
    {                                                                       \
        f16* d_ = sm + (c) * 32768 + 16384 + (h) * 8192 + stoff;            \
        gl_lds16(gB + (size_t)((h) * 128) * 2048 + (tt) * 64, d_);          \
        gl_lds16(gB + (size_t)((h) * 128 + 64) * 2048 + (tt) * 64, d_ + 4096); \
    }

    f32x4 acc[8][4];
#pragma unroll
    for (int mf = 0; mf < 8; ++mf)
#pragma unroll
        for (int nf = 0; nf < 4; ++nf)
#pragma unroll
            for (int r = 0; r < 4; ++r) acc[mf][nf][r] = 0.f;

    STG_A(0, 0, 0); STG_A(0, 1, 0); STG_B(0, 0, 0); STG_B(0, 1, 0);
    STG_A(1, 0, 1); STG_A(1, 1, 1);
    asm volatile("s_waitcnt vmcnt(4)" ::: "memory");   // tile 0 landed
    __builtin_amdgcn_s_barrier();
    asm volatile("" ::: "memory");

    const int aoff = kq * 128 + r16 * 8;   // frag-read lane offset (halfs)

    f16x8 af[8][2], bf[4][2];

    for (int kt = 0; kt < 32; ++kt) {
        const int cur = kt & 1, nxt = cur ^ 1;
        const f16* pa = sm + cur * 32768 + wr * 8192 + aoff;
        const f16* pb = sm + cur * 32768 + 16384 + (wc >> 1) * 8192 + (wc & 1) * 4096 + aoff;

        // ---------------- P1: af[0-3], bf[0-1]; stage B0(kt+1); MFMA m0n0
#pragma unroll
        for (int mf = 0; mf < 4; ++mf)
#pragma unroll
            for (int dk = 0; dk < 2; ++dk)
                af[mf][dk] = *(const f16x8*)(pa + mf * 1024 + dk * 512);
#pragma unroll
        for (int nf = 0; nf < 2; ++nf)
#pragma unroll
            for (int dk = 0; dk < 2; ++dk)
                bf[nf][dk] = *(const f16x8*)(pb + nf * 1024 + dk * 512);
        if (kt + 1 < 32) STG_B(nxt, 0, kt + 1);
        asm volatile("" ::: "memory");
        __builtin_amdgcn_s_barrier();
        asm volatile("s_waitcnt lgkmcnt(0)" ::: "memory");
        __builtin_amdgcn_sched_barrier(0);
        __builtin_amdgcn_s_setprio(1);
#pragma unroll
        for (int mf = 0; mf < 4; ++mf)
#pragma unroll
            for (int nf = 0; nf < 2; ++nf)
#pragma unroll
                for (int dk = 0; dk < 2; ++dk)
                    acc[mf][nf] = __builtin_amdgcn_mfma_f32_16x16x32_f16(
                        af[mf][dk], bf[nf][dk], acc[mf][nf], 0, 0, 0);
        __builtin_amdgcn_s_setprio(0);
        asm volatile("" ::: "memory");
        __builtin_amdgcn_s_barrier();
        asm volatile("" ::: "memory");

        // ---------------- P2: af[4-7]; stage B1(kt+1); MFMA m1n0
#pragma unroll
        for (int mf = 4; mf < 8; ++mf)
#pragma unroll
            for (int dk = 0; dk < 2; ++dk)
                af[mf][dk] = *(const f16x8*)(pa + mf * 1024 + dk * 512);
        if (kt + 1 < 32) STG_B(nxt, 1, kt + 1);
        asm volatile("" ::: "memory");
        __builtin_amdgcn_s_barrier();
        asm volatile("s_waitcnt lgkmcnt(0)" ::: "memory");
        __builtin_amdgcn_sched_barrier(0);
        __builtin_amdgcn_s_setprio(1);
#pragma unroll
        for (int mf = 4; mf < 8; ++mf)
#pragma unroll
            for (int nf = 0; nf < 2; ++nf)
#pragma unroll
                for (int dk = 0; dk < 2; ++dk)
                    acc[mf][nf] = __builtin_amdgcn_mfma_f32_16x16x32_f16(
                        af[mf][dk], bf[nf][dk], acc[mf][nf], 0, 0, 0);
        __builtin_amdgcn_s_setprio(0);
        asm volatile("" ::: "memory");
        __builtin_amdgcn_s_barrier();
        asm volatile("" ::: "memory");

        // ---------------- P3: bf[2-3]; stage A0(kt+2); MFMA m0n1
#pragma unroll
        for (int nf = 2; nf < 4; ++nf)
#pragma unroll
            for (int dk = 0; dk < 2; ++dk)
                bf[nf][dk] = *(const f16x8*)(pb + nf * 1024 + dk * 512);
        if (kt + 2 < 32) STG_A(cur, 0, kt + 2);
        asm volatile("" ::: "memory");
        __builtin_amdgcn_s_barrier();
        asm volatile("s_waitcnt lgkmcnt(0)" ::: "memory");
        __builtin_amdgcn_sched_barrier(0);
        __builtin_amdgcn_s_setprio(1);
#pragma unroll
        for (int mf = 0; mf < 4; ++mf)
#pragma unroll
            for (int nf = 2; nf < 4; ++nf)
#pragma unroll
                for (int dk = 0; dk < 2; ++dk)
                    acc[mf][nf] = __builtin_amdgcn_mfma_f32_16x16x32_f16(
                        af[mf][dk], bf[nf][dk], acc[mf][nf], 0, 0, 0);
        __builtin_amdgcn_s_setprio(0);
        asm volatile("" ::: "memory");
        __builtin_amdgcn_s_barrier();
        asm volatile("" ::: "memory");

        // ---------------- P4: stage A1(kt+2); vmcnt; MFMA m1n1
        if (kt + 2 < 32) STG_A(cur, 1, kt + 2);
        if (kt < 30) asm volatile("s_waitcnt vmcnt(4)" ::: "memory");
        else         asm volatile("s_waitcnt vmcnt(0)" ::: "memory");
        __builtin_amdgcn_s_barrier();
        asm volatile("" ::: "memory");
        __builtin_amdgcn_s_setprio(1);
#pragma unroll
        for (int mf = 4; mf < 8; ++mf)
#pragma unroll
            for (int nf = 2; nf < 4; ++nf)
#pragma unroll
                for (int dk = 0; dk < 2; ++dk)
                    acc[mf][nf] = __builtin_amdgcn_mfma_f32_16x16x32_f16(
                        af[mf][dk], bf[nf][dk], acc[mf][nf], 0, 0, 0);
        __builtin_amdgcn_s_setprio(0);
        asm volatile("" ::: "memory");
        __builtin_amdgcn_s_barrier();
        asm volatile("" ::: "memory");
    }
#undef STG_A
#undef STG_B

    // epilogue: C/D mapping col(n)=lane&15, row(m)=(lane>>4)*4+reg
    const int wm = wr * 128, wn = wc * 64;
#pragma unroll
    for (int nf = 0; nf < 4; ++nf) {
        int n = bn + wn + nf * 16 + r16;
        float bb = bias[n];
        int h = n >> 9, d = n & 511;
#pragma unroll
        for (int mf = 0; mf < 8; ++mf) {
            int mbase = bm + wm + mf * 16 + (lane >> 4) * 4;
            int b = mbase >> 9, s0 = mbase & 511;
            if (!tr) {
#pragma unroll
                for (int r = 0; r < 4; ++r)
                    dst[(((size_t)(b * 4 + h)) * 512 + s0 + r) * 512 + d] =
                        (f16)(acc[mf][nf][r] + bb);
            } else {
                f16 pk[4];
#pragma unroll
                for (int r = 0; r < 4; ++r) pk[r] = (f16)(acc[mf][nf][r] + bb);
                *(float2*)(dst + (((size_t)(b * 4 + h)) * 512 + d) * 512 + s0) =
                    *(float2*)pk;
            }
        }
    }
}

// ---------------------------------------------------------------- fused chain
// 512 threads, 8 waves; wave w owns a 64-col n-strip over ALL 128 rows:
// acc[4][2] f32x16 (128x64 per wave).  acc = Sb(128xK=512) @ Bsrc^T,
// Bsrc row-major [n][k] (ld=512).  B fragments load DIRECTLY global->VGPR
// (each wave's strip private, read once per block).  2-set pipeline,
// 16 panels fully unrolled (static set indices).
__device__ __forceinline__ void stage_ntr(const f16* __restrict__ Bsrc,
                                          const f16* __restrict__ Sb,
                                          int t, f32x16 acc[4][2])
{
    const int lane = t & 63;
    const int wave = t >> 6;
    const int l31  = lane & 31;
    const int l5   = (lane >> 5) * 8;

#pragma unroll
    for (int mt = 0; mt < 4; ++mt)
#pragma unroll
        for (int nt = 0; nt < 2; ++nt)
#pragma unroll
            for (int r = 0; r < 16; ++r) acc[mt][nt][r] = 0.f;

    const f16* b0 = Bsrc + (size_t)(wave * 64 + l31) * 512 + l5;
    const f16* b1 = Bsrc + (size_t)(wave * 64 + 32 + l31) * 512 + l5;

    f16x8 bfA[2][2], bfB[2][2];     // [nt][dkh]

#define LDP(S, pp)                                              \
    do {                                                        \
        S[0][0] = *(const f16x8*)(b0 + (pp) * 32);              \
        S[0][1] = *(const f16x8*)(b0 + (pp) * 32 + 16);         \
        S[1][0] = *(const f16x8*)(b1 + (pp) * 32);              \
        S[1][1] = *(const f16x8*)(b1 + (pp) * 32 + 16);         \
    } while (0)

    LDP(bfA, 0);
    LDP(bfB, 1);

#pragma unroll
    for (int p = 0; p < 16; ++p) {
        f16x8 (&S)[2][2] = (p & 1) ? bfB : bfA;   // static under full unroll
#pragma unroll
        for (int dkh = 0; dkh < 2; ++dkh) {
            f16x8 af0 = *(const f16x8*)(Sb + (size_t)l31 * SB_STRIDE + p * 32 + dkh * 16 + l5);
            f16x8 af1 = *(const f16x8*)(Sb + (size_t)(32 + l31) * SB_STRIDE + p * 32 + dkh * 16 + l5);
            f16x8 af2 = *(const f16x8*)(Sb + (size_t)(64 + l31) * SB_STRIDE + p * 32 + dkh * 16 + l5);
            f16x8 af3 = *(const f16x8*)(Sb + (size_t)(96 + l31) * SB_STRIDE + p * 32 + dkh * 16 + l5);
            acc[0][0] = __builtin_amdgcn_mfma_f32_32x32x16_f16(af0, S[0][dkh], acc[0][0], 0, 0, 0);
            acc[0][1] = __builtin_amdgcn_mfma_f32_32x32x16_f16(af0, S[1][dkh], acc[0][1], 0, 0, 0);
            acc[1][0] = __builtin_amdgcn_mfma_f32_32x32x16_f16(af1, S[0][dkh], acc[1][0], 0, 0, 0);
            acc[1][1] = __builtin_amdgcn_mfma_f32_32x32x16_f16(af1, S[1][dkh], acc[1][1], 0, 0, 0);
            acc[2][0] = __builtin_amdgcn_mfma_f32_32x32x16_f16(af2, S[0][dkh], acc[2][0], 0, 0, 0);
            acc[2][1] = __builtin_amdgcn_mfma_f32_32x32x16_f16(af2, S[1][dkh], acc[2][1], 0, 0, 0);
            acc[3][0] = __builtin_amdgcn_mfma_f32_32x32x16_f16(af3, S[0][dkh], acc[3][0], 0, 0, 0);
            acc[3][1] = __builtin_amdgcn_mfma_f32_32x32x16_f16(af3, S[1][dkh], acc[3][1], 0, 0, 0);
        }
        if (p + 2 < 16) LDP(S, p + 2);   // reload just-consumed set for p+2
    }
#undef LDP
}

// C/D mapping 32x32: col=lane&31, row=(reg&3)+8*(reg>>2)+4*(lane>>5)
__device__ __forceinline__ void emit_to_S(f16* __restrict__ Sb, const f32x16 acc[4][2],
                                          int t, float scale)
{
    const int lane = t & 63;
    const int wn = (t >> 6) * 64;
#pragma unroll
    for (int mt = 0; mt < 4; ++mt)
#pragma unroll
        for (int nt = 0; nt < 2; ++nt) {
            int col = wn + nt * 32 + (lane & 31);
#pragma unroll
            for (int r = 0; r < 16; ++r) {
                int row = mt * 32 + (r & 3) + 8 * (r >> 2) + 4 * (lane >> 5);
                Sb[(size_t)row * SB_STRIDE + col] = (f16)(acc[mt][nt][r] * scale);
            }
        }
}

// bhmask/q0shift: bh = bx & bhmask, q0 = (bx >> q0shift) * QBLK.
__global__ __launch_bounds__(512, 2) void chain_f16(
    const f16* __restrict__ q16, const f16* __restrict__ k16,
    const f16* __restrict__ ck16, const f16* __restrict__ vt16,
    const f16* __restrict__ cvt16, float* __restrict__ out,
    int bhmask, int q0shift)
{
    extern __shared__ f16 smem[];
    f16* Sb = smem;                       // [128][SB_STRIDE] = 133,120 B
    const int t = threadIdx.x;
    const int bh = blockIdx.x & bhmask;
    const int q0 = (blockIdx.x >> q0shift) * QBLK;
    const size_t SB = 512 * 512;

    // stage Q[q0..q0+128) into Sbuf
    const f16* Q = q16 + bh * SB;
    for (int i = t; i < 8192; i += 512) {
        int row = i >> 6, c = (i & 63) * 8;
        *(int4*)(Sb + (size_t)row * SB_STRIDE + c) =
            *(const int4*)(Q + (size_t)(q0 + row) * 512 + c);
    }
    __syncthreads();

    f32x16 acc[4][2];

    // S1 = Q @ K^T
    stage_ntr(k16 + bh * SB, Sb, t, acc);
    __syncthreads();                 // all Sb reads done before overwrite
    emit_to_S(Sb, acc, t, 1.0f);
    __syncthreads();

    // S2 = S1 @ CK^T * SCALE
    stage_ntr(ck16 + bh * SB, Sb, t, acc);
    __syncthreads();
    emit_to_S(Sb, acc, t, SCALE);
    __syncthreads();

    // softmax rows (wave w -> rows 16w..16w+16)
    {
        const int lane = t & 63;
        const int wave = t >> 6;
        for (int rr = 0; rr < 16; ++rr) {
            int r = wave * 16 + rr;
            f16x8 xv = *(const f16x8*)(Sb + (size_t)r * SB_STRIDE + lane * 8);
            float x[8];
            float mx = -1e30f;
#pragma unroll
            for (int j = 0; j < 8; ++j) { x[j] = (float)xv[j]; mx = fmaxf(mx, x[j]); }
#pragma unroll
            for (int o = 32; o > 0; o >>= 1) mx = fmaxf(mx, __shfl_xor(mx, o));
            float s = 0.f;
#pragma unroll
            for (int j = 0; j < 8; ++j) { x[j] = __expf(x[j] - mx); s += x[j]; }
#pragma unroll
            for (int o = 32; o > 0; o >>= 1) s += __shfl_xor(s, o);
            float inv = 1.0f / s;
            f16x8 ov;
#pragma unroll
            for (int j = 0; j < 8; ++j) ov[j] = (f16)(x[j] * inv);
            *(f16x8*)(Sb + (size_t)r * SB_STRIDE + lane * 8) = ov;
        }
    }
    __syncthreads();

    // C1 = P @ V   (Vt is [bh][d][s]: NT-ready)
    stage_ntr(vt16 + bh * SB, Sb, t, acc);
    __syncthreads();
    emit_to_S(Sb, acc, t, 1.0f);
    __syncthreads();

    // OUT = C1 @ CV (CVt NT-ready), merge-heads store f32
    stage_ntr(cvt16 + bh * SB, Sb, t, acc);
    {
        const int lane = t & 63;
        const int wn = (t >> 6) * 64;
        int b = bh >> 2, h = bh & 3;
#pragma unroll
        for (int mt = 0; mt < 4; ++mt)
#pragma unroll
            for (int nt = 0; nt < 2; ++nt) {
                int col = h * 512 + wn + nt * 32 + (lane & 31);
#pragma unroll
                for (int r = 0; r < 16; ++r) {
                    int row = q0 + mt * 32 + (r & 3) + 8 * (r >> 2) + 4 * (lane >> 5);
                    out[((size_t)b * 512 + row) * 2048 + col] = acc[mt][nt][r];
                }
            }
    }
}

// ---------------------------------------------------------------- host
extern "C" void kernel_launch(void* const* d_in, const int* in_sizes, int n_in,
                              void* d_out, int out_size, void* d_ws, size_t ws_size,
                              hipStream_t stream)
{
    const float* hs = (const float*)d_in[0];
    const float* Wf[5] = {(const float*)d_in[1], (const float*)d_in[3],
                          (const float*)d_in[5], (const float*)d_in[7],
                          (const float*)d_in[9]};
    const float* bf[5] = {(const float*)d_in[2], (const float*)d_in[4],
                          (const float*)d_in[6], (const float*)d_in[8],
                          (const float*)d_in[10]};
    float* out = (float*)d_out;

    hipFuncSetAttribute((const void*)chain_f16,
                        hipFuncAttributeMaxDynamicSharedMemorySize, CHAIN_LDS);
    hipFuncSetAttribute((const void*)proj_f16,
                        hipFuncAttributeMaxDynamicSharedMemorySize, PROJ_LDS);

    f16* ws = (f16*)d_ws;
    const size_t WELEM = 2048ULL * 2048;      // 4,194,304
    const size_t FULLACT = 64ULL * 512 * 512; // 16,777,216

    f16* W16[5];
    for (int i = 0; i < 5; ++i) W16[i] = ws + i * WELEM;
    f16* after_w = ws + 5 * WELEM;

    for (int i = 0; i < 5; ++i)
        conv_f32_f16<<<dim3(WELEM / 2048), 256, 0, stream>>>(Wf[i], W16[i], (int)WELEM);

    size_t full_need = (5 * WELEM + FULLACT + 5 * FULLACT) * sizeof(f16);  // 243,269,632
    if (ws_size >= full_need) {
        // ---------------- full path ----------------
        f16* hs16 = after_w;
        f16* act[5];
        for (int i = 0; i < 5; ++i) act[i] = after_w + FULLACT + i * FULLACT;

        conv_f32_f16<<<dim3(FULLACT / 2048), 256, 0, stream>>>(hs, hs16, (int)FULLACT);

        ProjPtrs P;
        for (int i = 0; i < 5; ++i) { P.W[i] = W16[i]; P.bias[i] = bf[i]; P.dst[i] = act[i]; }
        proj_f16<<<dim3(8, 32, 5), 512, PROJ_LDS, stream>>>(hs16, P);

        // act order: q,k,v^T,ck,cv^T -> chain(q,k,ck,vt,cvt)
        // 256 blocks: bh = bx & 63 (same XCD for a bh's 4 q0-blocks), q0 = (bx>>6)*128
        chain_f16<<<dim3(256), 512, CHAIN_LDS, stream>>>(
            act[0], act[1], act[3], act[2], act[4], out, 63, 6);
    } else {
        // ---------------- chunked path (54.5 MB ws) ----------------
        const size_t CHROW = 1048576ULL;      // 512*2048 elems per batch
        const size_t CHACT = 4ULL * 512 * 512;
        f16* hs16c = after_w;
        f16* act[5];
        for (int i = 0; i < 5; ++i) act[i] = after_w + CHROW + i * CHACT;

        ProjPtrs P;
        for (int i = 0; i < 5; ++i) { P.W[i] = W16[i]; P.bias[i] = bf[i]; P.dst[i] = act[i]; }

        for (int c = 0; c < 16; ++c) {
            conv_f32_f16<<<dim3(CHROW / 2048), 256, 0, stream>>>(
                hs + c * CHROW, hs16c, (int)CHROW);
            proj_f16<<<dim3(8, 2, 5), 512, PROJ_LDS, stream>>>(hs16c, P);
            chain_f16<<<dim3(16), 512, CHAIN_LDS, stream>>>(
                act[0], act[1], act[3], act[2], act[4], out + c * CHROW, 3, 2);
        }
    }

    (void)in_sizes; (void)n_in; (void)out_size;
}